// Round 3
// baseline (947.115 us; speedup 1.0000x reference)
//
#include <hip/hip_runtime.h>
#include <hip/hip_bf16.h>

// Problem constants
#define B_SZ   2
#define L_SEQ  2048
#define HIDD   2048
#define NH     16
#define QL     1536
#define KVLR   512
#define ROPE_D 64
#define NOPE_D 128
#define VD     128
#define QKD    192   // NOPE + ROPE

typedef __attribute__((ext_vector_type(8))) __bf16 bf16x8;
typedef __attribute__((ext_vector_type(4))) float  f32x4;
typedef __attribute__((ext_vector_type(8))) unsigned short u16x8;

__device__ __forceinline__ float bf2f(unsigned short u) {
    union { float f; unsigned int i; } x; x.i = ((unsigned int)u) << 16; return x.f;
}
__device__ __forceinline__ unsigned short f2bf(float f) {
    __hip_bfloat16 h = __float2bfloat16(f);
    return *reinterpret_cast<unsigned short*>(&h);
}
// NaN-safe clamp: IEEE fmin/fmax drop the NaN operand, so NaN -> -3.3e38.
__device__ __forceinline__ float finclamp(float v) {
    return fminf(fmaxf(v, -3.3e38f), 3.3e38f);
}

// ---------------------------------------------------------------------------
// Input-dtype detector. For little-endian fp32 data, u16[even] = low mantissa
// half -> exponent field uniform in [0,255]. For true bf16 ~N(0,s), exponent
// stays in [100,150]. Count outliers over 128 even slots.
// ---------------------------------------------------------------------------
__global__ void detect_fp32(const unsigned short* __restrict__ x, int* __restrict__ flag)
{
    if (threadIdx.x == 0 && blockIdx.x == 0) {
        int c = 0;
        for (int i = 0; i < 128; i++) {
            unsigned e = (x[2 * i] >> 7) & 0xFF;
            if (e > 150 || (e > 0 && e < 100)) c++;
        }
        *flag = (c >= 16) ? 1 : 0;
    }
}

// ---------------------------------------------------------------------------
// Convert input -> bf16 workspace copy. flag=1: src is fp32; flag=0: src is
// bf16 (plain copy). n8 = element count / 8 (all inputs divisible by 8).
// ---------------------------------------------------------------------------
__global__ __launch_bounds__(256)
void conv_bf16(const void* __restrict__ src, __hip_bfloat16* __restrict__ dst,
               long long n8, const int* __restrict__ flag)
{
    long long i = (long long)blockIdx.x * blockDim.x + threadIdx.x;
    long long stride = (long long)gridDim.x * blockDim.x;
    const int isf = *flag;
    for (; i < n8; i += stride) {
        u16x8 o;
        if (isf) {
            const float* s = (const float*)src + i * 8;
            float4 a = *(const float4*)s;
            float4 b = *(const float4*)(s + 4);
            o[0] = f2bf(a.x); o[1] = f2bf(a.y); o[2] = f2bf(a.z); o[3] = f2bf(a.w);
            o[4] = f2bf(b.x); o[5] = f2bf(b.y); o[6] = f2bf(b.z); o[7] = f2bf(b.w);
        } else {
            o = ((const u16x8*)src)[i];
        }
        ((u16x8*)dst)[i] = o;
    }
}

// ---------------------------------------------------------------------------
// Generic C = scale * (A . B^T): A (M,K) lda, B (N,K) ldb, C (M,N) ldc, bf16.
// 128x128 tile, BK=32, 256 threads (4 waves, 2x2 of 64x64), fp32 acc.
// Batched over grid.z. If (fp32out && *flagp) the output is stored as fp32.
// ---------------------------------------------------------------------------
#define LDS_STRIDE 40  // 32 + 8 pad: 2-way bank conflicts only, 16B-aligned rows

__global__ __launch_bounds__(256)
void gemm_bt(const __hip_bfloat16* __restrict__ A,
             const __hip_bfloat16* __restrict__ Bm,
             void* __restrict__ Cv,
             int M, int N, int K, int lda, int ldb, int ldc,
             float scale,
             int zdivA, long long zsA, int zmodB, long long zsB, long long zsC,
             const int* __restrict__ flagp, int fp32out)
{
    int z = blockIdx.z;
    A  += (long long)(z / zdivA) * zsA;
    Bm += (long long)(z % zmodB) * zsB;
    const long long coff = (long long)z * zsC;

    __shared__ __hip_bfloat16 As[128 * LDS_STRIDE];
    __shared__ __hip_bfloat16 Bs[128 * LDS_STRIDE];

    const int tid  = threadIdx.x;
    const int lane = tid & 63;
    const int wid  = tid >> 6;
    const int quad = lane >> 4;
    const int l15  = lane & 15;
    const int wm   = (wid >> 1) * 64;
    const int wn   = (wid & 1) * 64;

    const int m0 = blockIdx.y * 128;
    const int n0 = blockIdx.x * 128;

    f32x4 acc[4][4] = {};

    const int srow = tid >> 2;        // 0..63
    const int scol = (tid & 3) * 8;   // 0,8,16,24

    for (int k0 = 0; k0 < K; k0 += 32) {
        __syncthreads();
        for (int rr = 0; rr < 2; rr++) {
            int r = srow + rr * 64;
            u16x8 v = *reinterpret_cast<const u16x8*>(
                A + (long long)(m0 + r) * lda + k0 + scol);
            *reinterpret_cast<u16x8*>(&As[r * LDS_STRIDE + scol]) = v;
        }
        for (int rr = 0; rr < 2; rr++) {
            int r = srow + rr * 64;
            int gn = n0 + r;
            u16x8 v = {};
            if (gn < N)
                v = *reinterpret_cast<const u16x8*>(
                    Bm + (long long)gn * ldb + k0 + scol);
            *reinterpret_cast<u16x8*>(&Bs[r * LDS_STRIDE + scol]) = v;
        }
        __syncthreads();

        bf16x8 af[4], bfv[4];
        for (int mt = 0; mt < 4; mt++)
            af[mt] = *reinterpret_cast<const bf16x8*>(
                &As[(wm + mt * 16 + l15) * LDS_STRIDE + quad * 8]);
        for (int nt = 0; nt < 4; nt++)
            bfv[nt] = *reinterpret_cast<const bf16x8*>(
                &Bs[(wn + nt * 16 + l15) * LDS_STRIDE + quad * 8]);
        for (int mt = 0; mt < 4; mt++)
            for (int nt = 0; nt < 4; nt++)
                acc[mt][nt] = __builtin_amdgcn_mfma_f32_16x16x32_bf16(
                    af[mt], bfv[nt], acc[mt][nt], 0, 0, 0);
    }

    const int f32o = fp32out && (*flagp);

    // Epilogue: C/D layout col=lane&15, row=quad*4+reg  [m89/m91-verified]
    for (int mt = 0; mt < 4; mt++) {
        int row = m0 + wm + mt * 16 + quad * 4;
        for (int nt = 0; nt < 4; nt++) {
            int col = n0 + wn + nt * 16 + l15;
            if (col < N) {
                for (int r = 0; r < 4; r++) {
                    float val = finclamp(acc[mt][nt][r] * scale);
                    long long idx = coff + (long long)(row + r) * ldc + col;
                    if (f32o) ((float*)Cv)[idx] = val;
                    else      ((__hip_bfloat16*)Cv)[idx] = __float2bfloat16(val);
                }
            }
        }
    }
}

// ---------------------------------------------------------------------------
// In-place rmsnorm of rows of length QL=1536, weight vector w.
// ---------------------------------------------------------------------------
__global__ __launch_bounds__(256)
void rmsnorm_qa(__hip_bfloat16* __restrict__ X, const __hip_bfloat16* __restrict__ W)
{
    int row = blockIdx.x;
    __hip_bfloat16* xr = X + (long long)row * QL;
    int tid = threadIdx.x;
    bool act = tid < (QL / 8);
    float v[8];
    float ss = 0.f;
    if (act) {
        u16x8 raw = *reinterpret_cast<const u16x8*>(xr + tid * 8);
        for (int j = 0; j < 8; j++) {
            v[j] = bf2f(((const unsigned short*)&raw)[j]);
            ss += v[j] * v[j];
        }
    }
    for (int m = 1; m < 64; m <<= 1) ss += __shfl_xor(ss, m, 64);
    __shared__ float ws4[4];
    if ((tid & 63) == 0) ws4[tid >> 6] = ss;
    __syncthreads();
    float tot = ws4[0] + ws4[1] + ws4[2] + ws4[3];
    float inv = rsqrtf(tot / (float)QL + 1e-5f);
    if (act) {
        u16x8 wr = *reinterpret_cast<const u16x8*>(W + tid * 8);
        u16x8 o;
        for (int j = 0; j < 8; j++)
            ((unsigned short*)&o)[j] =
                f2bf(finclamp(v[j] * inv * bf2f(((const unsigned short*)&wr)[j])));
        *reinterpret_cast<u16x8*>(xr + tid * 8) = o;
    }
}

// ---------------------------------------------------------------------------
// kv path: kvl = rmsnorm(ckv[:,0:512]) * w * SKV(=2);  kpe = rope(ckv[:,512:576])
// grid = B*L rows, block = 64 (one wave).
// ---------------------------------------------------------------------------
__global__ __launch_bounds__(64)
void kv_norm_rope(const __hip_bfloat16* __restrict__ CKV,
                  const __hip_bfloat16* __restrict__ W,
                  __hip_bfloat16* __restrict__ KVLAT,
                  __hip_bfloat16* __restrict__ KPE)
{
    int row = blockIdx.x;
    int l = row & (L_SEQ - 1);
    int t = threadIdx.x;
    const __hip_bfloat16* cr = CKV + (long long)row * 576;

    float v[8]; float ss = 0.f;
    u16x8 raw = *reinterpret_cast<const u16x8*>(cr + t * 8);
    for (int j = 0; j < 8; j++) {
        v[j] = bf2f(((const unsigned short*)&raw)[j]);
        ss += v[j] * v[j];
    }
    for (int m = 1; m < 64; m <<= 1) ss += __shfl_xor(ss, m, 64);
    float inv = rsqrtf(ss / (float)KVLR + 1e-5f) * 2.0f;  // SKV = sqrt(2048/512) = 2
    u16x8 wr = *reinterpret_cast<const u16x8*>(W + t * 8);
    u16x8 o;
    for (int j = 0; j < 8; j++)
        ((unsigned short*)&o)[j] =
            f2bf(finclamp(v[j] * inv * bf2f(((const unsigned short*)&wr)[j])));
    *reinterpret_cast<u16x8*>(KVLAT + (long long)row * KVLR + t * 8) = o;

    if (t < 32) {
        float freq = powf(10000.0f, -(float)(2 * t) / 64.0f);
        float th = (float)l * freq;
        float c = cosf(th), s = sinf(th);
        float x1 = __bfloat162float(cr[512 + 2 * t]);
        float x2 = __bfloat162float(cr[512 + 2 * t + 1]);
        __hip_bfloat16* kp = KPE + (long long)row * 64;
        kp[2 * t]     = __float2bfloat16(finclamp(x1 * c - x2 * s));
        kp[2 * t + 1] = __float2bfloat16(finclamp(x1 * s + x2 * c));
    }
}

// ---------------------------------------------------------------------------
// In-place traditional RoPE on q_pe part of q (B*L, H*192), cols h*192+128..191
// ---------------------------------------------------------------------------
__global__ __launch_bounds__(256)
void rope_q(__hip_bfloat16* __restrict__ Q)
{
    int row = blockIdx.x;
    int l = row & (L_SEQ - 1);
    int tid = threadIdx.x;
    for (int p = tid; p < NH * 32; p += 256) {
        int h = p >> 5, i = p & 31;
        __hip_bfloat16* base = Q + (long long)row * (NH * QKD) + h * QKD + NOPE_D + 2 * i;
        float freq = powf(10000.0f, -(float)(2 * i) / 64.0f);
        float th = (float)l * freq;
        float c = cosf(th), s = sinf(th);
        float x1 = __bfloat162float(base[0]);
        float x2 = __bfloat162float(base[1]);
        base[0] = __float2bfloat16(finclamp(x1 * c - x2 * s));
        base[1] = __float2bfloat16(finclamp(x1 * s + x2 * c));
    }
}

// ---------------------------------------------------------------------------
// wB[h][n][k]: n<128 -> w_embed_q[h][k][n] transposed; rows 128..255 copied
// from w_unembed by copy_unembed. grid = (512/64, H), block = 256.
// ---------------------------------------------------------------------------
__global__ __launch_bounds__(256)
void transpose_embed(const __hip_bfloat16* __restrict__ WE,
                     __hip_bfloat16* __restrict__ WB)
{
    int h = blockIdx.y;
    int k0 = blockIdx.x * 64;
    __shared__ __hip_bfloat16 t[64][136];
    int tid = threadIdx.x;
    for (int it = 0; it < 4; it++) {
        int s = tid + it * 256;         // 1024 slots: 64 k-rows x 16 col-groups
        int k = s >> 4, cg = (s & 15) * 8;
        u16x8 v = *reinterpret_cast<const u16x8*>(
            WE + ((long long)h * KVLR + k0 + k) * NOPE_D + cg);
        *reinterpret_cast<u16x8*>(&t[k][cg]) = v;
    }
    __syncthreads();
    for (int it = 0; it < 4; it++) {
        int s = tid + it * 256;         // 1024 slots: 128 n-rows x 8 k-groups
        int n = s >> 3, kg = (s & 7) * 8;
        u16x8 o;
        for (int j = 0; j < 8; j++)
            ((unsigned short*)&o)[j] = *reinterpret_cast<unsigned short*>(&t[kg + j][n]);
        *reinterpret_cast<u16x8*>(WB + ((long long)h * 256 + n) * KVLR + k0 + kg) = o;
    }
}

__global__ __launch_bounds__(256)
void copy_unembed(const __hip_bfloat16* __restrict__ WU,
                  __hip_bfloat16* __restrict__ WB)
{
    int h = blockIdx.x;
    long long src = (long long)h * VD * KVLR;
    long long dst = ((long long)h * 256 + 128) * KVLR;
    for (int s = threadIdx.x; s < VD * KVLR / 8; s += 256) {
        u16x8 v = *reinterpret_cast<const u16x8*>(WU + src + s * 8);
        *reinterpret_cast<u16x8*>(WB + dst + s * 8) = v;
    }
}

// ---------------------------------------------------------------------------
// Flash attention. Q (B*L, H*192) pre-scaled by SQ*SCALE, roped.
// KV (B*H, L, 256) = [k(128) | v(128)].  KPE (B*L, 64) roped.
// O (B*L, H*128).  256 thr = 4 waves; block = 64 q rows of one (b,h);
// wave = 16 q rows; 64-key tiles, causal, online softmax (NaN-proof).
// ---------------------------------------------------------------------------
__global__ __launch_bounds__(256)
void flash_attn(const __hip_bfloat16* __restrict__ Q,
                const __hip_bfloat16* __restrict__ KV,
                const __hip_bfloat16* __restrict__ KPE,
                __hip_bfloat16* __restrict__ O)
{
    const int q0 = blockIdx.x * 64;
    const int bh = blockIdx.y;
    const int b = bh >> 4;
    const int h = bh & 15;

    __shared__ __hip_bfloat16 Ks[64 * 200];     // [key][0..191], stride 200
    __shared__ __hip_bfloat16 Vs[128 * 72];     // [vd][key], stride 72
    __shared__ __hip_bfloat16 Ps[4][16 * 72];   // per-wave P, stride 72

    const int tid  = threadIdx.x;
    const int lane = tid & 63;
    const int w    = tid >> 6;
    const int quad = lane >> 4;
    const int l15  = lane & 15;

    const __hip_bfloat16* KVb  = KV + (long long)bh * L_SEQ * 256;
    const __hip_bfloat16* KPEb = KPE + (long long)b * L_SEQ * 64;

    bf16x8 qf[6];
    {
        long long qoff = (long long)(b * L_SEQ + q0 + w * 16 + l15) * (NH * QKD) + h * QKD;
        for (int kk = 0; kk < 6; kk++)
            qf[kk] = *reinterpret_cast<const bf16x8*>(Q + qoff + kk * 32 + quad * 8);
    }

    f32x4 o_acc[8] = {};
    float m_run[4], l_run[4];
    for (int r = 0; r < 4; r++) { m_run[r] = -1e30f; l_run[r] = 0.f; }

    const int nkt = (q0 >> 6) + 1;
    for (int kt = 0; kt < nkt; kt++) {
        const int kk0 = kt * 64;
        __syncthreads();
        // stage K: 64 keys x 192 (128 from KV + 64 from KPE)
        for (int it = 0; it < 6; it++) {
            int s = tid + it * 256;                 // 1536 slots
            int r = s / 24, cg = s % 24;
            u16x8 v;
            if (cg < 16)
                v = *reinterpret_cast<const u16x8*>(
                    KVb + (long long)(kk0 + r) * 256 + cg * 8);
            else
                v = *reinterpret_cast<const u16x8*>(
                    KPEb + (long long)(kk0 + r) * 64 + (cg - 16) * 8);
            *reinterpret_cast<u16x8*>(&Ks[r * 200 + cg * 8]) = v;
        }
        // stage V transposed: Vs[vd][key]
        for (int it = 0; it < 4; it++) {
            int s = tid + it * 256;                 // 1024 slots
            int key = s >> 4, cg = (s & 15) * 8;
            u16x8 v = *reinterpret_cast<const u16x8*>(
                KVb + (long long)(kk0 + key) * 256 + 128 + cg);
            for (int j = 0; j < 8; j++)
                Vs[(cg + j) * 72 + key] = ((__hip_bfloat16*)&v)[j];
        }
        __syncthreads();

        // S = Q . K^T  (16 x 64)
        f32x4 sfr[4];
        for (int nt = 0; nt < 4; nt++) {
            f32x4 sacc = {};
            for (int kk = 0; kk < 6; kk++) {
                bf16x8 kf = *reinterpret_cast<const bf16x8*>(
                    &Ks[(nt * 16 + l15) * 200 + kk * 32 + quad * 8]);
                sacc = __builtin_amdgcn_mfma_f32_16x16x32_bf16(qf[kk], kf, sacc, 0, 0, 0);
            }
            sfr[nt] = sacc;
        }

        // causal tile row max over VALID entries only
        const int qrow_base = q0 + w * 16 + quad * 4;
        float tmax[4];
        for (int r = 0; r < 4; r++) tmax[r] = -1e30f;
        for (int nt = 0; nt < 4; nt++) {
            int key = kk0 + nt * 16 + l15;
            for (int r = 0; r < 4; r++) {
                float sv = fminf(fmaxf(sfr[nt][r], -1e30f), 1e30f); // NaN->-1e30
                sfr[nt][r] = sv;
                if (key <= qrow_base + r) tmax[r] = fmaxf(tmax[r], sv);
            }
        }
        for (int r = 0; r < 4; r++)
            for (int m = 1; m < 16; m <<= 1)
                tmax[r] = fmaxf(tmax[r], __shfl_xor(tmax[r], m, 16));

        float alpha[4], rs[4];
        for (int r = 0; r < 4; r++) {
            float mn = fmaxf(m_run[r], tmax[r]);
            alpha[r] = (m_run[r] <= -1e29f) ? 0.f : __expf(m_run[r] - mn);
            m_run[r] = mn;
            rs[r] = 0.f;
        }
        for (int nt = 0; nt < 4; nt++) {
            int key = kk0 + nt * 16 + l15;
            for (int r = 0; r < 4; r++) {
                float p = (key > qrow_base + r) ? 0.f
                          : __expf(sfr[nt][r] - m_run[r]);
                sfr[nt][r] = p;
                rs[r] += p;
            }
        }
        for (int r = 0; r < 4; r++) {
            float t = rs[r];
            for (int m = 1; m < 16; m <<= 1) t += __shfl_xor(t, m, 16);
            l_run[r] = l_run[r] * alpha[r] + t;
        }

        // P -> LDS (C-layout -> A-layout round trip)
        for (int nt = 0; nt < 4; nt++)
            for (int r = 0; r < 4; r++)
                Ps[w][(quad * 4 + r) * 72 + nt * 16 + l15] =
                    __float2bfloat16(sfr[nt][r]);

        // rescale O
        for (int vt = 0; vt < 8; vt++)
            for (int r = 0; r < 4; r++)
                o_acc[vt][r] *= alpha[r];

        // O += P . V   (K-dim = 64 keys, 2 MFMA k-steps)
        for (int ks = 0; ks < 2; ks++) {
            bf16x8 pf = *reinterpret_cast<const bf16x8*>(
                &Ps[w][l15 * 72 + ks * 32 + quad * 8]);
            for (int vt = 0; vt < 8; vt++) {
                bf16x8 vf = *reinterpret_cast<const bf16x8*>(
                    &Vs[(vt * 16 + l15) * 72 + ks * 32 + quad * 8]);
                o_acc[vt] = __builtin_amdgcn_mfma_f32_16x16x32_bf16(pf, vf, o_acc[vt], 0, 0, 0);
            }
        }
    }

    // epilogue: O / l  -> (B*L, H*128)
    const int orow = q0 + w * 16 + quad * 4;
    for (int r = 0; r < 4; r++) {
        float invl = 1.0f / fmaxf(l_run[r], 1e-30f);
        __hip_bfloat16* op = O + (long long)(b * L_SEQ + orow + r) * (NH * VD) + h * VD;
        for (int vt = 0; vt < 8; vt++)
            op[vt * 16 + l15] = __float2bfloat16(finclamp(o_acc[vt][r] * invl));
    }
}

// ---------------------------------------------------------------------------
extern "C" void kernel_launch(void* const* d_in, const int* in_sizes, int n_in,
                              void* d_out, int out_size, void* d_ws, size_t ws_size,
                              hipStream_t stream)
{
    // Size-based greedy input mapping (mask at any position is skipped).
    const long long want[9] = {
        8388608,   // x        (2,2048,2048)
        3145728,   // wq_a     (1536,2048)
        1536,      // q_a_ln_w
        4718592,   // wq_b     (3072,1536)
        1179648,   // wkv_a    (576,2048)
        512,       // kv_a_ln_w
        1048576,   // w_embed_q (16,512,128)
        1048576,   // w_unembed (16,128,512)
        4194304    // wo       (2048,2048)
    };
    const void* P[9] = {};
    {
        int j = 0;
        for (int i = 0; i < n_in && j < 9; i++)
            if ((long long)in_sizes[i] == want[j]) P[j++] = d_in[i];
        if (!P[8]) {
            const int map[9] = {0, 2, 3, 4, 5, 6, 7, 8, 9};
            for (int j2 = 0; j2 < 9; j2++) P[j2] = d_in[map[j2]];
        }
    }
    (void)ws_size; (void)out_size;

    // Workspace layout
    char* ws = (char*)d_ws;
    int* flag = (int*)ws;                                             // 256 B hdr
    long long off = 256;
    auto alloc = [&](long long elems) {
        __hip_bfloat16* p = (__hip_bfloat16*)(ws + off);
        off += ((elems * 2 + 255) / 256) * 256;
        return p;
    };
    // converted bf16 inputs (~47.5 MB)
    __hip_bfloat16* xc     = alloc(want[0]);
    __hip_bfloat16* wqac   = alloc(want[1]);
    __hip_bfloat16* qlnwc  = alloc(want[2]);
    __hip_bfloat16* wqbc   = alloc(want[3]);
    __hip_bfloat16* wkvac  = alloc(want[4]);
    __hip_bfloat16* kvlnwc = alloc(want[5]);
    __hip_bfloat16* wembc  = alloc(want[6]);
    __hip_bfloat16* wunec  = alloc(want[7]);
    __hip_bfloat16* woc    = alloc(want[8]);
    // pipeline buffers (~76 MB)
    const long long BL = (long long)B_SZ * L_SEQ;   // 4096
    __hip_bfloat16* kvbuf = alloc((long long)B_SZ * NH * L_SEQ * 256); // 33.5 MB
    __hip_bfloat16* kpe   = alloc(BL * 64);
    __hip_bfloat16* qbuf  = alloc(BL * NH * QKD);                      // 25.2 MB
    char* R4 = ws + off;                                               // reuse region
    __hip_bfloat16* ckv   = (__hip_bfloat16*)(R4);
    __hip_bfloat16* kvl   = (__hip_bfloat16*)(R4 + 4718592);
    __hip_bfloat16* wB    = (__hip_bfloat16*)(R4 + 8912896);
    __hip_bfloat16* q_a   = (__hip_bfloat16*)(R4);   // after kv phase
    __hip_bfloat16* aout  = (__hip_bfloat16*)(R4);   // after q_a dead

    // 0) detect input dtype, convert all inputs to bf16
    detect_fp32<<<1, 64, 0, stream>>>((const unsigned short*)P[0], flag);
    __hip_bfloat16* dsts[9] = {xc, wqac, qlnwc, wqbc, wkvac, kvlnwc, wembc, wunec, woc};
    for (int i = 0; i < 9; i++) {
        long long n8 = want[i] / 8;
        int grid = (int)((n8 + 255) / 256); if (grid > 2048) grid = 2048;
        conv_bf16<<<grid, 256, 0, stream>>>(P[i], dsts[i], n8, flag);
    }

    // ---- KV path ----
    gemm_bt<<<dim3(5, 32, 1), 256, 0, stream>>>(
        xc, wkvac, ckv, 4096, 576, 2048, 2048, 2048, 576, 1.0f,
        1, 0, 1, 0, 0, flag, 0);
    kv_norm_rope<<<4096, 64, 0, stream>>>(ckv, kvlnwc, kvl, kpe);
    transpose_embed<<<dim3(8, 16), 256, 0, stream>>>(wembc, wB);
    copy_unembed<<<16, 256, 0, stream>>>(wunec, wB);
    gemm_bt<<<dim3(2, 16, 32), 256, 0, stream>>>(
        kvl, wB, kvbuf, 2048, 256, 512, 512, 512, 256, 1.0f,
        NH, (long long)L_SEQ * KVLR, NH, 256LL * KVLR, (long long)L_SEQ * 256, flag, 0);

    // ---- Q path ----
    gemm_bt<<<dim3(12, 32, 1), 256, 0, stream>>>(
        xc, wqac, q_a, 4096, 1536, 2048, 2048, 2048, 1536, 1.0f,
        1, 0, 1, 0, 0, flag, 0);
    rmsnorm_qa<<<4096, 256, 0, stream>>>(q_a, qlnwc);
    gemm_bt<<<dim3(24, 32, 1), 256, 0, stream>>>(
        q_a, wqbc, qbuf, 4096, 3072, 1536, 1536, 1536, 3072, 1.0f / 12.0f,
        1, 0, 1, 0, 0, flag, 0);
    rope_q<<<4096, 256, 0, stream>>>(qbuf);

    // ---- Attention + output ----
    flash_attn<<<dim3(32, 32), 256, 0, stream>>>(qbuf, kvbuf, kpe, aout);
    // final GEMM: output dtype follows detected input dtype (fp32 ref -> fp32)
    gemm_bt<<<dim3(16, 32, 1), 256, 0, stream>>>(
        aout, woc, (void*)d_out, 4096, 2048, 2048, 2048, 2048, 2048, 1.0f,
        1, 0, 1, 0, 0, flag, 1);
}

// Round 4
// 669.317 us; speedup vs baseline: 1.4150x; 1.4150x over previous
//
#include <hip/hip_runtime.h>
#include <hip/hip_bf16.h>

// Problem constants
#define B_SZ   2
#define L_SEQ  2048
#define HIDD   2048
#define NH     16
#define QL     1536
#define KVLR   512
#define ROPE_D 64
#define NOPE_D 128
#define VD     128
#define QKD    192   // NOPE + ROPE

typedef __attribute__((ext_vector_type(8))) __bf16 bf16x8;
typedef __attribute__((ext_vector_type(4))) float  f32x4;
typedef __attribute__((ext_vector_type(8))) unsigned short u16x8;

__device__ __forceinline__ float bf2f(unsigned short u) {
    union { float f; unsigned int i; } x; x.i = ((unsigned int)u) << 16; return x.f;
}
__device__ __forceinline__ unsigned short f2bf(float f) {
    __hip_bfloat16 h = __float2bfloat16(f);
    return *reinterpret_cast<unsigned short*>(&h);
}
// NaN-safe clamp: IEEE fmin/fmax drop the NaN operand.
__device__ __forceinline__ float finclamp(float v) {
    return fminf(fmaxf(v, -3.3e38f), 3.3e38f);
}

// async global->LDS, 16B per lane; LDS dest = wave-uniform base + lane*16.
__device__ __forceinline__ void gld_lds16(const __hip_bfloat16* g, __hip_bfloat16* l)
{
    __builtin_amdgcn_global_load_lds(
        (const __attribute__((address_space(1))) unsigned int*)(g),
        (__attribute__((address_space(3))) unsigned int*)(l),
        16, 0, 0);
}

// ---------------------------------------------------------------------------
// Input-dtype detector (fp32 low-half u16 has wild exponent fields).
// ---------------------------------------------------------------------------
__global__ void detect_fp32(const unsigned short* __restrict__ x, int* __restrict__ flag)
{
    if (threadIdx.x == 0 && blockIdx.x == 0) {
        int c = 0;
        for (int i = 0; i < 128; i++) {
            unsigned e = (x[2 * i] >> 7) & 0xFF;
            if (e > 150 || (e > 0 && e < 100)) c++;
        }
        *flag = (c >= 16) ? 1 : 0;
    }
}

// ---------------------------------------------------------------------------
// Convert input -> bf16 workspace copy. flag=1: fp32 src; flag=0: bf16 copy.
// ---------------------------------------------------------------------------
__global__ __launch_bounds__(256)
void conv_bf16(const void* __restrict__ src, __hip_bfloat16* __restrict__ dst,
               long long n8, const int* __restrict__ flag)
{
    long long i = (long long)blockIdx.x * blockDim.x + threadIdx.x;
    long long stride = (long long)gridDim.x * blockDim.x;
    const int isf = *flag;
    for (; i < n8; i += stride) {
        u16x8 o;
        if (isf) {
            const float* s = (const float*)src + i * 8;
            float4 a = *(const float4*)s;
            float4 b = *(const float4*)(s + 4);
            o[0] = f2bf(a.x); o[1] = f2bf(a.y); o[2] = f2bf(a.z); o[3] = f2bf(a.w);
            o[4] = f2bf(b.x); o[5] = f2bf(b.y); o[6] = f2bf(b.z); o[7] = f2bf(b.w);
        } else {
            o = ((const u16x8*)src)[i];
        }
        ((u16x8*)dst)[i] = o;
    }
}

// ---------------------------------------------------------------------------
// C = scale*(A.B^T), bf16, m97-style: 128x128 tile, BK=32, global_load_lds
// 16B staging into unpadded stride-32 LDS. Batched over grid.z:
// offA = ((z/dA)%mA)*sA, offB = ((z/dB)%mB)*sB, offC = z*sC.
// M%128==0, K%32==0; N guarded (B row clamped, cols masked at epilogue).
// ---------------------------------------------------------------------------
__global__ __launch_bounds__(256)
void gemm_bt(const __hip_bfloat16* __restrict__ A,
             const __hip_bfloat16* __restrict__ Bm,
             void* __restrict__ Cv,
             int M, int N, int K, int lda, int ldb, int ldc,
             float scale,
             int dA, int mA, long long sA,
             int dB, int mB, long long sB, long long sC,
             const int* __restrict__ flagp, int fp32out)
{
    int z = blockIdx.z;
    A  += (long long)((z / dA) % mA) * sA;
    Bm += (long long)((z / dB) % mB) * sB;
    const long long coff = (long long)z * sC;

    __shared__ __hip_bfloat16 As[128 * 32];
    __shared__ __hip_bfloat16 Bs[128 * 32];

    const int tid  = threadIdx.x;
    const int lane = tid & 63;
    const int wid  = tid >> 6;
    const int quad = lane >> 4;
    const int l15  = lane & 15;
    const int wm   = (wid >> 1) * 64;
    const int wn   = (wid & 1) * 64;

    const int m0 = blockIdx.y * 128;
    const int n0 = blockIdx.x * 128;

    const int srow = lane >> 2;        // 0..15 within 16-row group
    const int scol = (lane & 3) * 8;   // 0,8,16,24

    f32x4 acc[4][4] = {};

    for (int k0 = 0; k0 < K; k0 += 32) {
        __syncthreads();
        // wave `wid` stages rows [wid*32, wid*32+32) of both tiles
        for (int i = 0; i < 2; i++) {
            int rbase = wid * 32 + i * 16;
            int r = rbase + srow;
            gld_lds16(A + (long long)(m0 + r) * lda + k0 + scol, &As[rbase * 32]);
            int gn = n0 + r; if (gn >= N) gn = N - 1;   // cols >= N discarded later
            gld_lds16(Bm + (long long)gn * ldb + k0 + scol, &Bs[rbase * 32]);
        }
        __syncthreads();   // waits vmcnt(0): staged data visible

        bf16x8 af[4], bfv[4];
        for (int mt = 0; mt < 4; mt++)
            af[mt] = *reinterpret_cast<const bf16x8*>(
                &As[(wm + mt * 16 + l15) * 32 + quad * 8]);
        for (int nt = 0; nt < 4; nt++)
            bfv[nt] = *reinterpret_cast<const bf16x8*>(
                &Bs[(wn + nt * 16 + l15) * 32 + quad * 8]);
        for (int mt = 0; mt < 4; mt++)
            for (int nt = 0; nt < 4; nt++)
                acc[mt][nt] = __builtin_amdgcn_mfma_f32_16x16x32_bf16(
                    af[mt], bfv[nt], acc[mt][nt], 0, 0, 0);
    }

    const int f32o = fp32out && (*flagp);

    // Epilogue: C/D layout col=lane&15, row=quad*4+reg  [m89/m91-verified]
    for (int mt = 0; mt < 4; mt++) {
        int row = m0 + wm + mt * 16 + quad * 4;
        for (int nt = 0; nt < 4; nt++) {
            int col = n0 + wn + nt * 16 + l15;
            if (col < N) {
                for (int r = 0; r < 4; r++) {
                    float val = finclamp(acc[mt][nt][r] * scale);
                    long long idx = coff + (long long)(row + r) * ldc + col;
                    if (f32o) ((float*)Cv)[idx] = val;
                    else      ((__hip_bfloat16*)Cv)[idx] = __float2bfloat16(val);
                }
            }
        }
    }
}

// ---------------------------------------------------------------------------
// In-place rmsnorm of rows of length QL=1536.
// ---------------------------------------------------------------------------
__global__ __launch_bounds__(256)
void rmsnorm_qa(__hip_bfloat16* __restrict__ X, const __hip_bfloat16* __restrict__ W)
{
    int row = blockIdx.x;
    __hip_bfloat16* xr = X + (long long)row * QL;
    int tid = threadIdx.x;
    bool act = tid < (QL / 8);
    float v[8];
    float ss = 0.f;
    if (act) {
        u16x8 raw = *reinterpret_cast<const u16x8*>(xr + tid * 8);
        for (int j = 0; j < 8; j++) {
            v[j] = bf2f(((const unsigned short*)&raw)[j]);
            ss += v[j] * v[j];
        }
    }
    for (int m = 1; m < 64; m <<= 1) ss += __shfl_xor(ss, m, 64);
    __shared__ float ws4[4];
    if ((tid & 63) == 0) ws4[tid >> 6] = ss;
    __syncthreads();
    float tot = ws4[0] + ws4[1] + ws4[2] + ws4[3];
    float inv = rsqrtf(tot / (float)QL + 1e-5f);
    if (act) {
        u16x8 wr = *reinterpret_cast<const u16x8*>(W + tid * 8);
        u16x8 o;
        for (int j = 0; j < 8; j++)
            ((unsigned short*)&o)[j] =
                f2bf(finclamp(v[j] * inv * bf2f(((const unsigned short*)&wr)[j])));
        *reinterpret_cast<u16x8*>(xr + tid * 8) = o;
    }
}

// ---------------------------------------------------------------------------
// kvl = rmsnorm(ckv[:,0:512])*w*2;  kpe = rope(ckv[:,512:576])
// ---------------------------------------------------------------------------
__global__ __launch_bounds__(64)
void kv_norm_rope(const __hip_bfloat16* __restrict__ CKV,
                  const __hip_bfloat16* __restrict__ W,
                  __hip_bfloat16* __restrict__ KVLAT,
                  __hip_bfloat16* __restrict__ KPE)
{
    int row = blockIdx.x;
    int l = row & (L_SEQ - 1);
    int t = threadIdx.x;
    const __hip_bfloat16* cr = CKV + (long long)row * 576;

    float v[8]; float ss = 0.f;
    u16x8 raw = *reinterpret_cast<const u16x8*>(cr + t * 8);
    for (int j = 0; j < 8; j++) {
        v[j] = bf2f(((const unsigned short*)&raw)[j]);
        ss += v[j] * v[j];
    }
    for (int m = 1; m < 64; m <<= 1) ss += __shfl_xor(ss, m, 64);
    float inv = rsqrtf(ss / (float)KVLR + 1e-5f) * 2.0f;  // SKV = 2
    u16x8 wr = *reinterpret_cast<const u16x8*>(W + t * 8);
    u16x8 o;
    for (int j = 0; j < 8; j++)
        ((unsigned short*)&o)[j] =
            f2bf(finclamp(v[j] * inv * bf2f(((const unsigned short*)&wr)[j])));
    *reinterpret_cast<u16x8*>(KVLAT + (long long)row * KVLR + t * 8) = o;

    if (t < 32) {
        float freq = powf(10000.0f, -(float)(2 * t) / 64.0f);
        float th = (float)l * freq;
        float c = cosf(th), s = sinf(th);
        float x1 = __bfloat162float(cr[512 + 2 * t]);
        float x2 = __bfloat162float(cr[512 + 2 * t + 1]);
        __hip_bfloat16* kp = KPE + (long long)row * 64;
        kp[2 * t]     = __float2bfloat16(finclamp(x1 * c - x2 * s));
        kp[2 * t + 1] = __float2bfloat16(finclamp(x1 * s + x2 * c));
    }
}

// ---------------------------------------------------------------------------
// In-place traditional RoPE on q_pe cols h*192+128..191.
// ---------------------------------------------------------------------------
__global__ __launch_bounds__(256)
void rope_q(__hip_bfloat16* __restrict__ Q)
{
    int row = blockIdx.x;
    int l = row & (L_SEQ - 1);
    int tid = threadIdx.x;
    for (int p = tid; p < NH * 32; p += 256) {
        int h = p >> 5, i = p & 31;
        __hip_bfloat16* base = Q + (long long)row * (NH * QKD) + h * QKD + NOPE_D + 2 * i;
        float freq = powf(10000.0f, -(float)(2 * i) / 64.0f);
        float th = (float)l * freq;
        float c = cosf(th), s = sinf(th);
        float x1 = __bfloat162float(base[0]);
        float x2 = __bfloat162float(base[1]);
        base[0] = __float2bfloat16(finclamp(x1 * c - x2 * s));
        base[1] = __float2bfloat16(finclamp(x1 * s + x2 * c));
    }
}

// ---------------------------------------------------------------------------
// wBk[h][n][k] = w_embed_q[h][k][n]  (H,128,512). grid=(8,16), block=256.
// ---------------------------------------------------------------------------
__global__ __launch_bounds__(256)
void transpose_embed(const __hip_bfloat16* __restrict__ WE,
                     __hip_bfloat16* __restrict__ WB)
{
    int h = blockIdx.y;
    int k0 = blockIdx.x * 64;
    __shared__ __hip_bfloat16 t[64][136];
    int tid = threadIdx.x;
    for (int it = 0; it < 4; it++) {
        int s = tid + it * 256;
        int k = s >> 4, cg = (s & 15) * 8;
        u16x8 v = *reinterpret_cast<const u16x8*>(
            WE + ((long long)h * KVLR + k0 + k) * NOPE_D + cg);
        *reinterpret_cast<u16x8*>(&t[k][cg]) = v;
    }
    __syncthreads();
    for (int it = 0; it < 4; it++) {
        int s = tid + it * 256;
        int n = s >> 3, kg = (s & 7) * 8;
        u16x8 o;
        for (int j = 0; j < 8; j++)
            ((unsigned short*)&o)[j] = *reinterpret_cast<unsigned short*>(&t[kg + j][n]);
        *reinterpret_cast<u16x8*>(WB + ((long long)h * 128 + n) * KVLR + k0 + kg) = o;
    }
}

// ---------------------------------------------------------------------------
// Flash attention. Q (B*L, H*192) pre-scaled, roped.
// Kb (B*H, L, 128); Vt (B*H, 128, L)  <-- V pre-transposed by vexp GEMM.
// KPE (B, L, 64) roped.  O (B*L, H*128).
// 256 thr = 4 waves; block = 64 q rows of one (b,h); wave = 16 q rows;
// 64-key tiles, causal, online softmax.
// ---------------------------------------------------------------------------
__global__ __launch_bounds__(256)
void flash_attn(const __hip_bfloat16* __restrict__ Q,
                const __hip_bfloat16* __restrict__ Kb,
                const __hip_bfloat16* __restrict__ Vt,
                const __hip_bfloat16* __restrict__ KPE,
                __hip_bfloat16* __restrict__ O)
{
    const int q0 = (gridDim.x - 1 - blockIdx.x) * 64;   // longest blocks first
    const int bh = blockIdx.y;
    const int b = bh >> 4;
    const int h = bh & 15;

    __shared__ __hip_bfloat16 Ks[64 * 200];     // [key][0..191], stride 200
    __shared__ __hip_bfloat16 Vs[128 * 72];     // [vd][key], stride 72
    __shared__ __hip_bfloat16 Ps[4][16 * 72];   // per-wave P, stride 72

    const int tid  = threadIdx.x;
    const int lane = tid & 63;
    const int w    = tid >> 6;
    const int quad = lane >> 4;
    const int l15  = lane & 15;

    const __hip_bfloat16* Kbh  = Kb + (long long)bh * L_SEQ * 128;
    const __hip_bfloat16* Vth  = Vt + (long long)bh * 128 * L_SEQ;
    const __hip_bfloat16* KPEb = KPE + (long long)b * L_SEQ * 64;

    bf16x8 qf[6];
    {
        long long qoff = (long long)(b * L_SEQ + q0 + w * 16 + l15) * (NH * QKD) + h * QKD;
        for (int kk = 0; kk < 6; kk++)
            qf[kk] = *reinterpret_cast<const bf16x8*>(Q + qoff + kk * 32 + quad * 8);
    }

    f32x4 o_acc[8] = {};
    float m_run[4], l_run[4];
    for (int r = 0; r < 4; r++) { m_run[r] = -1e30f; l_run[r] = 0.f; }

    const int nkt = (q0 >> 6) + 1;
    for (int kt = 0; kt < nkt; kt++) {
        const int kk0 = kt * 64;
        __syncthreads();
        // stage K: 64 keys x 192 (128 from Kb + 64 from KPE), vec8
        for (int it = 0; it < 6; it++) {
            int s = tid + it * 256;                 // 1536 slots
            int r = s / 24, cg = s % 24;
            u16x8 v;
            if (cg < 16)
                v = *reinterpret_cast<const u16x8*>(
                    Kbh + (long long)(kk0 + r) * 128 + cg * 8);
            else
                v = *reinterpret_cast<const u16x8*>(
                    KPEb + (long long)(kk0 + r) * 64 + (cg - 16) * 8);
            *reinterpret_cast<u16x8*>(&Ks[r * 200 + cg * 8]) = v;
        }
        // stage V^T: straight vec8 copy (conflict-free)
        for (int it = 0; it < 4; it++) {
            int s = tid + it * 256;                 // 1024 slots
            int vd = s >> 3, kg = (s & 7) * 8;
            u16x8 v = *reinterpret_cast<const u16x8*>(
                Vth + (long long)vd * L_SEQ + kk0 + kg);
            *reinterpret_cast<u16x8*>(&Vs[vd * 72 + kg]) = v;
        }
        __syncthreads();

        // S = Q . K^T  (16 x 64)
        f32x4 sfr[4];
        for (int nt = 0; nt < 4; nt++) {
            f32x4 sacc = {};
            for (int kk = 0; kk < 6; kk++) {
                bf16x8 kf = *reinterpret_cast<const bf16x8*>(
                    &Ks[(nt * 16 + l15) * 200 + kk * 32 + quad * 8]);
                sacc = __builtin_amdgcn_mfma_f32_16x16x32_bf16(qf[kk], kf, sacc, 0, 0, 0);
            }
            sfr[nt] = sacc;
        }

        // causal tile row max over VALID entries only
        const int qrow_base = q0 + w * 16 + quad * 4;
        float tmax[4];
        for (int r = 0; r < 4; r++) tmax[r] = -1e30f;
        for (int nt = 0; nt < 4; nt++) {
            int key = kk0 + nt * 16 + l15;
            for (int r = 0; r < 4; r++) {
                float sv = fminf(fmaxf(sfr[nt][r], -1e30f), 1e30f);
                sfr[nt][r] = sv;
                if (key <= qrow_base + r) tmax[r] = fmaxf(tmax[r], sv);
            }
        }
        for (int r = 0; r < 4; r++)
            for (int m = 1; m < 16; m <<= 1)
                tmax[r] = fmaxf(tmax[r], __shfl_xor(tmax[r], m, 16));

        float alpha[4], rs[4];
        for (int r = 0; r < 4; r++) {
            float mn = fmaxf(m_run[r], tmax[r]);
            alpha[r] = (m_run[r] <= -1e29f) ? 0.f : __expf(m_run[r] - mn);
            m_run[r] = mn;
            rs[r] = 0.f;
        }
        for (int nt = 0; nt < 4; nt++) {
            int key = kk0 + nt * 16 + l15;
            for (int r = 0; r < 4; r++) {
                float p = (key > qrow_base + r) ? 0.f
                          : __expf(sfr[nt][r] - m_run[r]);
                sfr[nt][r] = p;
                rs[r] += p;
            }
        }
        for (int r = 0; r < 4; r++) {
            float t = rs[r];
            for (int m = 1; m < 16; m <<= 1) t += __shfl_xor(t, m, 16);
            l_run[r] = l_run[r] * alpha[r] + t;
        }

        // P -> LDS (C-layout -> A-layout round trip)
        for (int nt = 0; nt < 4; nt++)
            for (int r = 0; r < 4; r++)
                Ps[w][(quad * 4 + r) * 72 + nt * 16 + l15] =
                    __float2bfloat16(sfr[nt][r]);

        // rescale O
        for (int vt = 0; vt < 8; vt++)
            for (int r = 0; r < 4; r++)
                o_acc[vt][r] *= alpha[r];

        // O += P . V
        for (int ks = 0; ks < 2; ks++) {
            bf16x8 pf = *reinterpret_cast<const bf16x8*>(
                &Ps[w][l15 * 72 + ks * 32 + quad * 8]);
            for (int vt = 0; vt < 8; vt++) {
                bf16x8 vf = *reinterpret_cast<const bf16x8*>(
                    &Vs[(vt * 16 + l15) * 72 + ks * 32 + quad * 8]);
                o_acc[vt] = __builtin_amdgcn_mfma_f32_16x16x32_bf16(pf, vf, o_acc[vt], 0, 0, 0);
            }
        }
    }

    // epilogue: O / l
    const int orow = q0 + w * 16 + quad * 4;
    for (int r = 0; r < 4; r++) {
        float invl = 1.0f / fmaxf(l_run[r], 1e-30f);
        __hip_bfloat16* op = O + (long long)(b * L_SEQ + orow + r) * (NH * VD) + h * VD;
        for (int vt = 0; vt < 8; vt++)
            op[vt * 16 + l15] = __float2bfloat16(finclamp(o_acc[vt][r] * invl));
    }
}

// ---------------------------------------------------------------------------
extern "C" void kernel_launch(void* const* d_in, const int* in_sizes, int n_in,
                              void* d_out, int out_size, void* d_ws, size_t ws_size,
                              hipStream_t stream)
{
    const long long want[9] = {
        8388608, 3145728, 1536, 4718592, 1179648, 512, 1048576, 1048576, 4194304
    };
    const void* P[9] = {};
    {
        int j = 0;
        for (int i = 0; i < n_in && j < 9; i++)
            if ((long long)in_sizes[i] == want[j]) P[j++] = d_in[i];
        if (!P[8]) {
            const int map[9] = {0, 2, 3, 4, 5, 6, 7, 8, 9};
            for (int j2 = 0; j2 < 9; j2++) P[j2] = d_in[map[j2]];
        }
    }
    (void)ws_size; (void)out_size;

    char* ws = (char*)d_ws;
    int* flag = (int*)ws;
    long long off = 256;
    auto alloc = [&](long long elems) {
        __hip_bfloat16* p = (__hip_bfloat16*)(ws + off);
        off += ((elems * 2 + 255) / 256) * 256;
        return p;
    };
    __hip_bfloat16* xc     = alloc(want[0]);
    __hip_bfloat16* wqac   = alloc(want[1]);
    __hip_bfloat16* qlnwc  = alloc(want[2]);
    __hip_bfloat16* wqbc   = alloc(want[3]);
    __hip_bfloat16* wkvac  = alloc(want[4]);
    __hip_bfloat16* kvlnwc = alloc(want[5]);
    __hip_bfloat16* wembc  = alloc(want[6]);
    __hip_bfloat16* wunec  = alloc(want[7]);
    __hip_bfloat16* woc    = alloc(want[8]);

    const long long BL = (long long)B_SZ * L_SEQ;   // 4096
    __hip_bfloat16* kvK  = alloc((long long)B_SZ * NH * L_SEQ * 128);  // 16.8 MB
    __hip_bfloat16* kvVt = alloc((long long)B_SZ * NH * 128 * L_SEQ);  // 16.8 MB
    __hip_bfloat16* kpe  = alloc(BL * 64);
    __hip_bfloat16* qbuf = alloc(BL * NH * QKD);                       // 25.2 MB
    char* R4 = ws + off;                                               // reuse region
    __hip_bfloat16* ckv  = (__hip_bfloat16*)(R4);
    __hip_bfloat16* kvl  = (__hip_bfloat16*)(R4 + 4718592);
    __hip_bfloat16* wBk  = (__hip_bfloat16*)(R4 + 8912896);            // (H,128,512)
    __hip_bfloat16* q_a  = (__hip_bfloat16*)(R4);   // after kv phase
    __hip_bfloat16* aout = (__hip_bfloat16*)(R4);   // after q_a dead

    // 0) detect dtype + convert inputs to bf16
    detect_fp32<<<1, 64, 0, stream>>>((const unsigned short*)P[0], flag);
    __hip_bfloat16* dsts[9] = {xc, wqac, qlnwc, wqbc, wkvac, kvlnwc, wembc, wunec, woc};
    for (int i = 0; i < 9; i++) {
        long long n8 = want[i] / 8;
        int grid = (int)((n8 + 255) / 256); if (grid > 2048) grid = 2048;
        conv_bf16<<<grid, 256, 0, stream>>>(P[i], dsts[i], n8, flag);
    }

    // ---- KV path ----
    gemm_bt<<<dim3(5, 32, 1), 256, 0, stream>>>(
        xc, wkvac, ckv, 4096, 576, 2048, 2048, 2048, 576, 1.0f,
        1, 1, 0, 1, 1, 0, 0, flag, 0);
    kv_norm_rope<<<4096, 64, 0, stream>>>(ckv, kvlnwc, kvl, kpe);
    transpose_embed<<<dim3(8, 16), 256, 0, stream>>>(wembc, wBk);
    // K-expand: per (b,h): kvK = kvl[b] @ wBk[h]^T  (2048,128,512)
    gemm_bt<<<dim3(1, 16, 32), 256, 0, stream>>>(
        kvl, wBk, kvK, 2048, 128, 512, 512, 512, 128, 1.0f,
        16, 2, (long long)L_SEQ * KVLR, 1, 16, 128LL * KVLR,
        (long long)L_SEQ * 128, flag, 0);
    // V-expand (transposed output): per (b,h): kvVt = wune[h] @ kvl[b]^T  (128,2048,512)
    gemm_bt<<<dim3(16, 1, 32), 256, 0, stream>>>(
        wunec, kvl, kvVt, 128, 2048, 512, 512, 512, 2048, 1.0f,
        1, 16, 128LL * KVLR, 16, 2, (long long)L_SEQ * KVLR,
        128LL * L_SEQ, flag, 0);

    // ---- Q path ----
    gemm_bt<<<dim3(12, 32, 1), 256, 0, stream>>>(
        xc, wqac, q_a, 4096, 1536, 2048, 2048, 2048, 1536, 1.0f,
        1, 1, 0, 1, 1, 0, 0, flag, 0);
    rmsnorm_qa<<<4096, 256, 0, stream>>>(q_a, qlnwc);
    gemm_bt<<<dim3(24, 32, 1), 256, 0, stream>>>(
        q_a, wqbc, qbuf, 4096, 3072, 1536, 1536, 1536, 3072, 1.0f / 12.0f,
        1, 1, 0, 1, 1, 0, 0, flag, 0);
    rope_q<<<4096, 256, 0, stream>>>(qbuf);

    // ---- Attention + output ----
    flash_attn<<<dim3(32, 32), 256, 0, stream>>>(qbuf, kvK, kvVt, kpe, aout);
    gemm_bt<<<dim3(16, 32, 1), 256, 0, stream>>>(
        aout, woc, (void*)d_out, 4096, 2048, 2048, 2048, 2048, 2048, 1.0f,
        1, 1, 0, 1, 1, 0, 0, flag, 1);
}